// Round 1
// baseline (5751.241 us; speedup 1.0000x reference)
//
#include <hip/hip_runtime.h>

#define GEMM_ROWS 32

// C[N,128] = (relu_in ? relu(A) : A)[N,128] @ W[128,128]
__global__ __launch_bounds__(256) void gemm_nn128(
    const float* __restrict__ A, const float* __restrict__ W,
    float* __restrict__ C, int N, int relu_in)
{
    __shared__ float sW[128 * 128];       // 64 KB
    __shared__ float sA[GEMM_ROWS * 128]; // 16 KB

    const float4* W4 = (const float4*)W;
    float4* sW4 = (float4*)sW;
    #pragma unroll
    for (int i = 0; i < 16; ++i)
        sW4[threadIdx.x + 256 * i] = W4[threadIdx.x + 256 * i];

    int row0 = blockIdx.x * GEMM_ROWS;
    int nrows = N - row0; if (nrows > GEMM_ROWS) nrows = GEMM_ROWS;
    const float4* A4 = (const float4*)(A + (size_t)row0 * 128);
    float4* sA4 = (float4*)sA;
    for (int i = threadIdx.x; i < nrows * 32; i += 256) {
        float4 v = A4[i];
        if (relu_in) {
            v.x = fmaxf(v.x, 0.f); v.y = fmaxf(v.y, 0.f);
            v.z = fmaxf(v.z, 0.f); v.w = fmaxf(v.w, 0.f);
        }
        sA4[i] = v;
    }
    __syncthreads();

    int c4 = threadIdx.x & 31;        // output col group: cols 4*c4 .. 4*c4+3
    int r0 = (threadIdx.x >> 5) * 4;  // rows r0 .. r0+3
    float4 acc0 = {0,0,0,0}, acc1 = {0,0,0,0}, acc2 = {0,0,0,0}, acc3 = {0,0,0,0};

    #pragma unroll 8
    for (int k4 = 0; k4 < 32; ++k4) {
        float4 w0 = sW4[(k4*4+0)*32 + c4];
        float4 w1 = sW4[(k4*4+1)*32 + c4];
        float4 w2 = sW4[(k4*4+2)*32 + c4];
        float4 w3 = sW4[(k4*4+3)*32 + c4];
        #define ROW_FMA(acc, i) { \
            float4 a = sA4[(r0+(i))*32 + k4]; \
            acc.x += a.x*w0.x + a.y*w1.x + a.z*w2.x + a.w*w3.x; \
            acc.y += a.x*w0.y + a.y*w1.y + a.z*w2.y + a.w*w3.y; \
            acc.z += a.x*w0.z + a.y*w1.z + a.z*w2.z + a.w*w3.z; \
            acc.w += a.x*w0.w + a.y*w1.w + a.z*w2.w + a.w*w3.w; }
        ROW_FMA(acc0, 0) ROW_FMA(acc1, 1) ROW_FMA(acc2, 2) ROW_FMA(acc3, 3)
        #undef ROW_FMA
    }

    float4* C4 = (float4*)(C + (size_t)row0 * 128);
    if (r0 + 0 < nrows) C4[(r0+0)*32 + c4] = acc0;
    if (r0 + 1 < nrows) C4[(r0+1)*32 + c4] = acc1;
    if (r0 + 2 < nrows) C4[(r0+2)*32 + c4] = acc2;
    if (r0 + 3 < nrows) C4[(r0+3)*32 + c4] = acc3;
}

// H[dst[e]] += X[src[e]]  (per edge, 128 f32). 32 lanes per edge, float4 each.
__global__ __launch_bounds__(256) void edge_scatter(
    const float4* __restrict__ X, const int* __restrict__ src,
    const int* __restrict__ dst, float* __restrict__ H, int E)
{
    long long tid = (long long)blockIdx.x * 256 + threadIdx.x;
    int e = (int)(tid >> 5);
    if (e >= E) return;
    int c = (int)(tid & 31);
    int s = src[e], d = dst[e];
    float4 v = X[(size_t)s * 32 + c];
    float* hp = H + (size_t)d * 128 + (size_t)c * 4;
    unsafeAtomicAdd(hp + 0, v.x);
    unsafeAtomicAdd(hp + 1, v.y);
    unsafeAtomicAdd(hp + 2, v.z);
    unsafeAtomicAdd(hp + 3, v.w);
}

// Per-graph sums via LDS staging; graph_ids sorted -> few graphs per block.
#define POOL_NODES 1024
__global__ __launch_bounds__(256) void pool_kernel(
    const float* __restrict__ H, const int* __restrict__ gid,
    float* __restrict__ pooled, float* __restrict__ counts, int N)
{
    __shared__ float sp[64 * 128]; // 32 KB
    __shared__ float sc[64];
    for (int i = threadIdx.x; i < 64 * 128; i += 256) sp[i] = 0.f;
    if (threadIdx.x < 64) sc[threadIdx.x] = 0.f;
    __syncthreads();

    int n0 = blockIdx.x * POOL_NODES;
    int nend = n0 + POOL_NODES; if (nend > N) nend = N;
    int lane = threadIdx.x & 63;
    int wave = threadIdx.x >> 6;
    const float2* H2 = (const float2*)H;
    for (int n = n0 + wave; n < nend; n += 4) {
        int g = gid[n];
        float2 v = H2[(size_t)n * 64 + lane];
        atomicAdd(&sp[g * 128 + lane * 2 + 0], v.x);
        atomicAdd(&sp[g * 128 + lane * 2 + 1], v.y);
        if (lane == 0) atomicAdd(&sc[g], 1.0f);
    }
    __syncthreads();

    for (int g = 0; g < 64; ++g) {
        if (sc[g] != 0.0f) {
            if (threadIdx.x < 128)
                unsafeAtomicAdd(&pooled[g * 128 + threadIdx.x], sp[g * 128 + threadIdx.x]);
            else if (threadIdx.x == 128)
                unsafeAtomicAdd(&counts[g], sc[g]);
        }
    }
}

// out[g,o] = sigmoid( (pooled[g,:]/max(counts[g],1)) . W3[:,o] )
__global__ __launch_bounds__(1024) void final_fc(
    const float* __restrict__ pooled, const float* __restrict__ counts,
    const float* __restrict__ W3, float* __restrict__ out)
{
    int t = threadIdx.x;          // 0..1023
    int g = t >> 4, o = t & 15;
    float cnt = fmaxf(counts[g], 1.0f);
    float acc = 0.f;
    #pragma unroll 16
    for (int k = 0; k < 128; ++k)
        acc += pooled[g * 128 + k] * W3[k * 16 + o];
    acc /= cnt;
    out[g * 16 + o] = 1.0f / (1.0f + __expf(-acc));
}

extern "C" void kernel_launch(void* const* d_in, const int* in_sizes, int n_in,
                              void* d_out, int out_size, void* d_ws, size_t ws_size,
                              hipStream_t stream)
{
    const float* features = (const float*)d_in[0];
    const float* W1       = (const float*)d_in[1];
    const float* W2       = (const float*)d_in[2];
    const float* W3       = (const float*)d_in[3];
    const int*   src      = (const int*)d_in[4];
    const int*   dst      = (const int*)d_in[5];
    const int*   gid      = (const int*)d_in[6];
    int N = in_sizes[0] / 128;
    int E = in_sizes[4];
    float* out = (float*)d_out;

    size_t bufBytes = (size_t)N * 128 * sizeof(float);
    char* ws = (char*)d_ws;
    float* bufA   = (float*)ws;                   // xw / h1w
    float* bufB   = (float*)(ws + bufBytes);      // h1 / h2
    float* pooled = (float*)(ws + 2 * bufBytes);  // 64*128
    float* counts = pooled + 64 * 128;            // 64

    int gemmGrid = (N + GEMM_ROWS - 1) / GEMM_ROWS;
    int edgeGrid = (E + 7) / 8; // 8 edges per 256-thread block (32 lanes/edge)

    // conv1: xw = features @ W1
    gemm_nn128<<<gemmGrid, 256, 0, stream>>>(features, W1, bufA, N, 0);
    // h1 = segment_sum(xw[src], dst)
    hipMemsetAsync(bufB, 0, bufBytes, stream);
    edge_scatter<<<edgeGrid, 256, 0, stream>>>((const float4*)bufA, src, dst, bufB, E);
    // conv2 transform: h1w = relu(h1) @ W2
    gemm_nn128<<<gemmGrid, 256, 0, stream>>>(bufB, W2, bufA, N, 1);
    // h2 = segment_sum(h1w[src], dst)
    hipMemsetAsync(bufB, 0, bufBytes, stream);
    edge_scatter<<<edgeGrid, 256, 0, stream>>>((const float4*)bufA, src, dst, bufB, E);
    // per-graph mean + fc + sigmoid
    hipMemsetAsync(pooled, 0, (64 * 128 + 64) * sizeof(float), stream);
    pool_kernel<<<(N + POOL_NODES - 1) / POOL_NODES, 256, 0, stream>>>(bufB, gid, pooled, counts, N);
    final_fc<<<1, 1024, 0, stream>>>(pooled, counts, W3, out);
}

// Round 2
// 812.494 us; speedup vs baseline: 7.0785x; 7.0785x over previous
//
#include <hip/hip_runtime.h>

#define GEMM_ROWS 32

// C[N,128] = (relu_in ? relu(A) : A)[N,128] @ W[128,128]
__global__ __launch_bounds__(256) void gemm_nn128(
    const float* __restrict__ A, const float* __restrict__ W,
    float* __restrict__ C, int N, int relu_in)
{
    __shared__ float sW[128 * 128];       // 64 KB
    __shared__ float sA[GEMM_ROWS * 128]; // 16 KB

    const float4* W4 = (const float4*)W;
    float4* sW4 = (float4*)sW;
    #pragma unroll
    for (int i = 0; i < 16; ++i)
        sW4[threadIdx.x + 256 * i] = W4[threadIdx.x + 256 * i];

    int row0 = blockIdx.x * GEMM_ROWS;
    int nrows = N - row0; if (nrows > GEMM_ROWS) nrows = GEMM_ROWS;
    const float4* A4 = (const float4*)(A + (size_t)row0 * 128);
    float4* sA4 = (float4*)sA;
    for (int i = threadIdx.x; i < nrows * 32; i += 256) {
        float4 v = A4[i];
        if (relu_in) {
            v.x = fmaxf(v.x, 0.f); v.y = fmaxf(v.y, 0.f);
            v.z = fmaxf(v.z, 0.f); v.w = fmaxf(v.w, 0.f);
        }
        sA4[i] = v;
    }
    __syncthreads();

    int c4 = threadIdx.x & 31;        // output col group: cols 4*c4 .. 4*c4+3
    int r0 = (threadIdx.x >> 5) * 4;  // rows r0 .. r0+3
    float4 acc0 = {0,0,0,0}, acc1 = {0,0,0,0}, acc2 = {0,0,0,0}, acc3 = {0,0,0,0};

    #pragma unroll 8
    for (int k4 = 0; k4 < 32; ++k4) {
        float4 w0 = sW4[(k4*4+0)*32 + c4];
        float4 w1 = sW4[(k4*4+1)*32 + c4];
        float4 w2 = sW4[(k4*4+2)*32 + c4];
        float4 w3 = sW4[(k4*4+3)*32 + c4];
        #define ROW_FMA(acc, i) { \
            float4 a = sA4[(r0+(i))*32 + k4]; \
            acc.x += a.x*w0.x + a.y*w1.x + a.z*w2.x + a.w*w3.x; \
            acc.y += a.x*w0.y + a.y*w1.y + a.z*w2.y + a.w*w3.y; \
            acc.z += a.x*w0.z + a.y*w1.z + a.z*w2.z + a.w*w3.z; \
            acc.w += a.x*w0.w + a.y*w1.w + a.z*w2.w + a.w*w3.w; }
        ROW_FMA(acc0, 0) ROW_FMA(acc1, 1) ROW_FMA(acc2, 2) ROW_FMA(acc3, 3)
        #undef ROW_FMA
    }

    float4* C4 = (float4*)(C + (size_t)row0 * 128);
    if (r0 + 0 < nrows) C4[(r0+0)*32 + c4] = acc0;
    if (r0 + 1 < nrows) C4[(r0+1)*32 + c4] = acc1;
    if (r0 + 2 < nrows) C4[(r0+2)*32 + c4] = acc2;
    if (r0 + 3 < nrows) C4[(r0+3)*32 + c4] = acc3;
}

// ---------- CSR build ----------

__global__ __launch_bounds__(256) void hist_kernel(
    const int* __restrict__ dst, int* __restrict__ deg, int E)
{
    int e = blockIdx.x * 256 + threadIdx.x;
    if (e < E) atomicAdd(&deg[dst[e]], 1);
}

// per-1024-block partial sums of deg
__global__ __launch_bounds__(1024) void scan_partial(
    const int* __restrict__ deg, int* __restrict__ bsums, int N)
{
    __shared__ int sw[16];
    int idx = blockIdx.x * 1024 + threadIdx.x;
    int v = (idx < N) ? deg[idx] : 0;
    #pragma unroll
    for (int o = 32; o; o >>= 1) v += __shfl_down(v, o, 64);
    if ((threadIdx.x & 63) == 0) sw[threadIdx.x >> 6] = v;
    __syncthreads();
    if (threadIdx.x < 16) {
        int x = sw[threadIdx.x];
        #pragma unroll
        for (int o = 8; o; o >>= 1) x += __shfl_down(x, o, 16);
        if (threadIdx.x == 0) bsums[blockIdx.x] = x;
    }
}

// in-place exclusive scan of the (small) block sums
__global__ void scan_exclusive_small(int* bsums, int nb)
{
    if (threadIdx.x == 0) {
        int run = 0;
        for (int i = 0; i < nb; ++i) { int t = bsums[i]; bsums[i] = run; run += t; }
    }
}

// final exclusive scan: off[idx] for idx in [0, N] (off[N] == E falls out)
__global__ __launch_bounds__(1024) void scan_final(
    const int* __restrict__ deg, const int* __restrict__ bsums,
    int* __restrict__ off, int N)
{
    __shared__ int s[1024];
    int t = threadIdx.x;
    int idx = blockIdx.x * 1024 + t;
    int v = (idx < N) ? deg[idx] : 0;
    s[t] = v;
    __syncthreads();
    #pragma unroll
    for (int o = 1; o < 1024; o <<= 1) {
        int x = (t >= o) ? s[t - o] : 0;
        __syncthreads();
        s[t] += x;
        __syncthreads();
    }
    if (idx <= N) off[idx] = s[t] - v + bsums[blockIdx.x];
}

__global__ __launch_bounds__(256) void fill_kernel(
    const int* __restrict__ src, const int* __restrict__ dst,
    int* __restrict__ cursor, int* __restrict__ col, int E)
{
    int e = blockIdx.x * 256 + threadIdx.x;
    if (e < E) {
        int pos = atomicAdd(&cursor[dst[e]], 1);
        col[pos] = src[e];
    }
}

// ---------- CSR aggregation: H[v] = sum_{e: dst=v} X[col[e]] ----------
// 32 lanes per node, one float4 column slice per lane.
__global__ __launch_bounds__(256) void csr_agg(
    const float4* __restrict__ X, const int* __restrict__ off,
    const int* __restrict__ col, float4* __restrict__ H, int N)
{
    int v = blockIdx.x * 8 + (threadIdx.x >> 5);
    if (v >= N) return;
    int lane = threadIdx.x & 31;
    int beg = off[v], end = off[v + 1];
    float4 acc = {0.f, 0.f, 0.f, 0.f};
    for (int i = beg; i < end; ++i) {
        int s = col[i];
        float4 x = X[(size_t)s * 32 + lane];
        acc.x += x.x; acc.y += x.y; acc.z += x.z; acc.w += x.w;
    }
    H[(size_t)v * 32 + lane] = acc;
}

// ---------- pooling + fc ----------

#define POOL_NODES 1024
__global__ __launch_bounds__(256) void pool_kernel(
    const float* __restrict__ H, const int* __restrict__ gid,
    float* __restrict__ pooled, float* __restrict__ counts, int N)
{
    __shared__ float sp[64 * 128]; // 32 KB
    __shared__ float sc[64];
    for (int i = threadIdx.x; i < 64 * 128; i += 256) sp[i] = 0.f;
    if (threadIdx.x < 64) sc[threadIdx.x] = 0.f;
    __syncthreads();

    int n0 = blockIdx.x * POOL_NODES;
    int nend = n0 + POOL_NODES; if (nend > N) nend = N;
    int lane = threadIdx.x & 63;
    int wave = threadIdx.x >> 6;
    const float2* H2 = (const float2*)H;
    for (int n = n0 + wave; n < nend; n += 4) {
        int g = gid[n];
        float2 v = H2[(size_t)n * 64 + lane];
        atomicAdd(&sp[g * 128 + lane * 2 + 0], v.x);
        atomicAdd(&sp[g * 128 + lane * 2 + 1], v.y);
        if (lane == 0) atomicAdd(&sc[g], 1.0f);
    }
    __syncthreads();

    for (int g = 0; g < 64; ++g) {
        if (sc[g] != 0.0f) {
            if (threadIdx.x < 128)
                unsafeAtomicAdd(&pooled[g * 128 + threadIdx.x], sp[g * 128 + threadIdx.x]);
            else if (threadIdx.x == 128)
                unsafeAtomicAdd(&counts[g], sc[g]);
        }
    }
}

__global__ __launch_bounds__(1024) void final_fc(
    const float* __restrict__ pooled, const float* __restrict__ counts,
    const float* __restrict__ W3, float* __restrict__ out)
{
    int t = threadIdx.x;          // 0..1023
    int g = t >> 4, o = t & 15;
    float cnt = fmaxf(counts[g], 1.0f);
    float acc = 0.f;
    #pragma unroll 16
    for (int k = 0; k < 128; ++k)
        acc += pooled[g * 128 + k] * W3[k * 16 + o];
    acc /= cnt;
    out[g * 16 + o] = 1.0f / (1.0f + __expf(-acc));
}

extern "C" void kernel_launch(void* const* d_in, const int* in_sizes, int n_in,
                              void* d_out, int out_size, void* d_ws, size_t ws_size,
                              hipStream_t stream)
{
    const float* features = (const float*)d_in[0];
    const float* W1       = (const float*)d_in[1];
    const float* W2       = (const float*)d_in[2];
    const float* W3       = (const float*)d_in[3];
    const int*   src      = (const int*)d_in[4];
    const int*   dst      = (const int*)d_in[5];
    const int*   gid      = (const int*)d_in[6];
    int N = in_sizes[0] / 128;
    int E = in_sizes[4];
    float* out = (float*)d_out;

    size_t bufBytes = (size_t)N * 128 * sizeof(float);
    char* ws = (char*)d_ws;
    size_t p = 0;
    auto alloc = [&](size_t bytes) { void* r = ws + p; p = (p + bytes + 255) & ~(size_t)255; return r; };
    float* bufA   = (float*)alloc(bufBytes);           // xw / h1w
    float* bufB   = (float*)alloc(bufBytes);           // h1 / h2
    float* pooled = (float*)alloc(64 * 128 * sizeof(float));
    float* counts = (float*)alloc(64 * sizeof(float));
    int*   deg    = (int*)alloc((size_t)N * sizeof(int));
    int*   off    = (int*)alloc((size_t)(N + 1) * sizeof(int));
    int*   cursor = (int*)alloc((size_t)N * sizeof(int));
    int*   col    = (int*)alloc((size_t)E * sizeof(int));
    int*   bsums  = (int*)alloc(256 * sizeof(int));

    int gemmGrid = (N + GEMM_ROWS - 1) / GEMM_ROWS;
    int edgeGrid = (E + 255) / 256;
    int aggGrid  = (N + 7) / 8;
    int scanGrid = (N + 1024) / 1024; // covers idx == N too

    // ---- CSR build (by dst) ----
    hipMemsetAsync(deg, 0, (size_t)N * sizeof(int), stream);
    hist_kernel<<<edgeGrid, 256, 0, stream>>>(dst, deg, E);
    scan_partial<<<scanGrid, 1024, 0, stream>>>(deg, bsums, N);
    scan_exclusive_small<<<1, 64, 0, stream>>>(bsums, scanGrid);
    scan_final<<<scanGrid, 1024, 0, stream>>>(deg, bsums, off, N);
    hipMemcpyAsync(cursor, off, (size_t)N * sizeof(int), hipMemcpyDeviceToDevice, stream);
    fill_kernel<<<edgeGrid, 256, 0, stream>>>(src, dst, cursor, col, E);

    // ---- conv1: xw = features @ W1 ; h1 = csr_agg(xw) ----
    gemm_nn128<<<gemmGrid, 256, 0, stream>>>(features, W1, bufA, N, 0);
    csr_agg<<<aggGrid, 256, 0, stream>>>((const float4*)bufA, off, col, (float4*)bufB, N);

    // ---- conv2: h1w = relu(h1) @ W2 ; h2 = csr_agg(h1w) ----
    gemm_nn128<<<gemmGrid, 256, 0, stream>>>(bufB, W2, bufA, N, 1);
    csr_agg<<<aggGrid, 256, 0, stream>>>((const float4*)bufA, off, col, (float4*)bufB, N);

    // ---- per-graph mean + fc + sigmoid ----
    hipMemsetAsync(pooled, 0, (64 * 128 + 64) * sizeof(float), stream);
    pool_kernel<<<(N + POOL_NODES - 1) / POOL_NODES, 256, 0, stream>>>(bufB, gid, pooled, counts, N);
    final_fc<<<1, 1024, 0, stream>>>(pooled, counts, W3, out);
}

// Round 3
// 654.641 us; speedup vs baseline: 8.7853x; 1.2411x over previous
//
#include <hip/hip_runtime.h>

#define GEMM_ROWS 32

// C[N,128] = (relu_in ? relu(A) : A)[N,128] @ W[128,128]
__global__ __launch_bounds__(256) void gemm_nn128(
    const float* __restrict__ A, const float* __restrict__ W,
    float* __restrict__ C, int N, int relu_in)
{
    __shared__ float sW[128 * 128];       // 64 KB
    __shared__ float sA[GEMM_ROWS * 128]; // 16 KB

    const float4* W4 = (const float4*)W;
    float4* sW4 = (float4*)sW;
    #pragma unroll
    for (int i = 0; i < 16; ++i)
        sW4[threadIdx.x + 256 * i] = W4[threadIdx.x + 256 * i];

    int row0 = blockIdx.x * GEMM_ROWS;
    int nrows = N - row0; if (nrows > GEMM_ROWS) nrows = GEMM_ROWS;
    const float4* A4 = (const float4*)(A + (size_t)row0 * 128);
    float4* sA4 = (float4*)sA;
    for (int i = threadIdx.x; i < nrows * 32; i += 256) {
        float4 v = A4[i];
        if (relu_in) {
            v.x = fmaxf(v.x, 0.f); v.y = fmaxf(v.y, 0.f);
            v.z = fmaxf(v.z, 0.f); v.w = fmaxf(v.w, 0.f);
        }
        sA4[i] = v;
    }
    __syncthreads();

    int c4 = threadIdx.x & 31;        // output col group: cols 4*c4 .. 4*c4+3
    int r0 = (threadIdx.x >> 5) * 4;  // rows r0 .. r0+3
    float4 acc0 = {0,0,0,0}, acc1 = {0,0,0,0}, acc2 = {0,0,0,0}, acc3 = {0,0,0,0};

    #pragma unroll 8
    for (int k4 = 0; k4 < 32; ++k4) {
        float4 w0 = sW4[(k4*4+0)*32 + c4];
        float4 w1 = sW4[(k4*4+1)*32 + c4];
        float4 w2 = sW4[(k4*4+2)*32 + c4];
        float4 w3 = sW4[(k4*4+3)*32 + c4];
        #define ROW_FMA(acc, i) { \
            float4 a = sA4[(r0+(i))*32 + k4]; \
            acc.x += a.x*w0.x + a.y*w1.x + a.z*w2.x + a.w*w3.x; \
            acc.y += a.x*w0.y + a.y*w1.y + a.z*w2.y + a.w*w3.y; \
            acc.z += a.x*w0.z + a.y*w1.z + a.z*w2.z + a.w*w3.z; \
            acc.w += a.x*w0.w + a.y*w1.w + a.z*w2.w + a.w*w3.w; }
        ROW_FMA(acc0, 0) ROW_FMA(acc1, 1) ROW_FMA(acc2, 2) ROW_FMA(acc3, 3)
        #undef ROW_FMA
    }

    float4* C4 = (float4*)(C + (size_t)row0 * 128);
    if (r0 + 0 < nrows) C4[(r0+0)*32 + c4] = acc0;
    if (r0 + 1 < nrows) C4[(r0+1)*32 + c4] = acc1;
    if (r0 + 2 < nrows) C4[(r0+2)*32 + c4] = acc2;
    if (r0 + 3 < nrows) C4[(r0+3)*32 + c4] = acc3;
}

// ---------- CSR build ----------

__global__ __launch_bounds__(256) void hist_kernel(
    const int* __restrict__ dst, int* __restrict__ deg, int E)
{
    int e = blockIdx.x * 256 + threadIdx.x;
    if (e < E) atomicAdd(&deg[dst[e]], 1);
}

__global__ __launch_bounds__(1024) void scan_partial(
    const int* __restrict__ deg, int* __restrict__ bsums, int N)
{
    __shared__ int sw[16];
    int idx = blockIdx.x * 1024 + threadIdx.x;
    int v = (idx < N) ? deg[idx] : 0;
    #pragma unroll
    for (int o = 32; o; o >>= 1) v += __shfl_down(v, o, 64);
    if ((threadIdx.x & 63) == 0) sw[threadIdx.x >> 6] = v;
    __syncthreads();
    if (threadIdx.x < 16) {
        int x = sw[threadIdx.x];
        #pragma unroll
        for (int o = 8; o; o >>= 1) x += __shfl_down(x, o, 16);
        if (threadIdx.x == 0) bsums[blockIdx.x] = x;
    }
}

__global__ void scan_exclusive_small(int* bsums, int nb)
{
    if (threadIdx.x == 0) {
        int run = 0;
        for (int i = 0; i < nb; ++i) { int t = bsums[i]; bsums[i] = run; run += t; }
    }
}

__global__ __launch_bounds__(1024) void scan_final(
    const int* __restrict__ deg, const int* __restrict__ bsums,
    int* __restrict__ off, int N)
{
    __shared__ int s[1024];
    int t = threadIdx.x;
    int idx = blockIdx.x * 1024 + t;
    int v = (idx < N) ? deg[idx] : 0;
    s[t] = v;
    __syncthreads();
    #pragma unroll
    for (int o = 1; o < 1024; o <<= 1) {
        int x = (t >= o) ? s[t - o] : 0;
        __syncthreads();
        s[t] += x;
        __syncthreads();
    }
    if (idx <= N) off[idx] = s[t] - v + bsums[blockIdx.x];
}

__global__ __launch_bounds__(256) void fill_kernel(
    const int* __restrict__ src, const int* __restrict__ dst,
    int* __restrict__ cursor, int* __restrict__ col, int E)
{
    int e = blockIdx.x * 256 + threadIdx.x;
    if (e < E) {
        int pos = atomicAdd(&cursor[dst[e]], 1);
        col[pos] = src[e];
    }
}

// ---------- CSR aggregation: H[v] = sum_{e: dst=v} X[col[e]] ----------
__global__ __launch_bounds__(256) void csr_agg(
    const float4* __restrict__ X, const int* __restrict__ off,
    const int* __restrict__ col, float4* __restrict__ H, int N)
{
    int v = blockIdx.x * 8 + (threadIdx.x >> 5);
    if (v >= N) return;
    int lane = threadIdx.x & 31;
    int beg = off[v], end = off[v + 1];
    float4 acc = {0.f, 0.f, 0.f, 0.f};
    int i = beg;
    for (; i + 1 < end; i += 2) {
        int s0 = col[i], s1 = col[i + 1];
        float4 x0 = X[(size_t)s0 * 32 + lane];
        float4 x1 = X[(size_t)s1 * 32 + lane];
        acc.x += x0.x + x1.x; acc.y += x0.y + x1.y;
        acc.z += x0.z + x1.z; acc.w += x0.w + x1.w;
    }
    if (i < end) {
        int s0 = col[i];
        float4 x0 = X[(size_t)s0 * 32 + lane];
        acc.x += x0.x; acc.y += x0.y; acc.z += x0.z; acc.w += x0.w;
    }
    H[(size_t)v * 32 + lane] = acc;
}

// ---------- pooling: register accumulate, flush on gid change ----------
// gid is sorted; each thread owns a float2 column slice over a node stripe.
#define POOL_CHUNK 128
__global__ __launch_bounds__(256) void pool_kernel(
    const float2* __restrict__ H2, const int* __restrict__ gid,
    float* __restrict__ pooled, int N)
{
    int c = threadIdx.x & 63;       // float2 col: cols 2c, 2c+1
    int stripe = threadIdx.x >> 6;  // 0..3
    int n0 = blockIdx.x * POOL_CHUNK;
    int nend = n0 + POOL_CHUNK; if (nend > N) nend = N;
    float2 acc = {0.f, 0.f};
    int curg = -1;
    for (int n = n0 + stripe; n < nend; n += 4) {
        int g = gid[n];
        float2 v = H2[(size_t)n * 64 + c];
        if (g != curg) {
            if (curg >= 0) {
                unsafeAtomicAdd(&pooled[curg * 128 + 2 * c],     acc.x);
                unsafeAtomicAdd(&pooled[curg * 128 + 2 * c + 1], acc.y);
            }
            curg = g; acc.x = 0.f; acc.y = 0.f;
        }
        acc.x += v.x; acc.y += v.y;
    }
    if (curg >= 0) {
        unsafeAtomicAdd(&pooled[curg * 128 + 2 * c],     acc.x);
        unsafeAtomicAdd(&pooled[curg * 128 + 2 * c + 1], acc.y);
    }
}

// out[g,o] = sigmoid( (pooled[g,:] . W3[:,o]) / count[g] ); counts via
// binary search over sorted gid.
__global__ __launch_bounds__(1024) void final_fc(
    const float* __restrict__ pooled, const int* __restrict__ gid, int N,
    const float* __restrict__ W3, float* __restrict__ out)
{
    __shared__ int lb[65];
    int t = threadIdx.x;
    if (t <= 64) {
        int lo = 0, hi = N;
        while (lo < hi) { int mid = (lo + hi) >> 1; if (gid[mid] < t) lo = mid + 1; else hi = mid; }
        lb[t] = lo;
    }
    __syncthreads();
    int g = t >> 4, o = t & 15;
    float cnt = fmaxf((float)(lb[g + 1] - lb[g]), 1.0f);
    float acc = 0.f;
    #pragma unroll 16
    for (int k = 0; k < 128; ++k)
        acc += pooled[g * 128 + k] * W3[k * 16 + o];
    acc /= cnt;
    out[g * 16 + o] = 1.0f / (1.0f + __expf(-acc));
}

extern "C" void kernel_launch(void* const* d_in, const int* in_sizes, int n_in,
                              void* d_out, int out_size, void* d_ws, size_t ws_size,
                              hipStream_t stream)
{
    const float* features = (const float*)d_in[0];
    const float* W1       = (const float*)d_in[1];
    const float* W2       = (const float*)d_in[2];
    const float* W3       = (const float*)d_in[3];
    const int*   src      = (const int*)d_in[4];
    const int*   dst      = (const int*)d_in[5];
    const int*   gid      = (const int*)d_in[6];
    int N = in_sizes[0] / 128;
    int E = in_sizes[4];
    float* out = (float*)d_out;

    size_t bufBytes = (size_t)N * 128 * sizeof(float);
    char* ws = (char*)d_ws;
    size_t p = 0;
    auto alloc = [&](size_t bytes) { void* r = ws + p; p = (p + bytes + 255) & ~(size_t)255; return r; };
    float* bufA   = (float*)alloc(bufBytes);           // xw / h1w
    float* bufB   = (float*)alloc(bufBytes);           // h1 / h2
    float* pooled = (float*)alloc(64 * 128 * sizeof(float));
    int*   deg    = (int*)alloc((size_t)N * sizeof(int));
    int*   off    = (int*)alloc((size_t)(N + 1) * sizeof(int));
    int*   cursor = (int*)alloc((size_t)N * sizeof(int));
    int*   col    = (int*)alloc((size_t)E * sizeof(int));
    int*   bsums  = (int*)alloc(256 * sizeof(int));

    int gemmGrid = (N + GEMM_ROWS - 1) / GEMM_ROWS;
    int edgeGrid = (E + 255) / 256;
    int aggGrid  = (N + 7) / 8;
    int scanGrid = (N + 1024) / 1024; // covers idx == N too

    // ---- CSR build (by dst) ----
    hipMemsetAsync(deg, 0, (size_t)N * sizeof(int), stream);
    hist_kernel<<<edgeGrid, 256, 0, stream>>>(dst, deg, E);
    scan_partial<<<scanGrid, 1024, 0, stream>>>(deg, bsums, N);
    scan_exclusive_small<<<1, 64, 0, stream>>>(bsums, scanGrid);
    scan_final<<<scanGrid, 1024, 0, stream>>>(deg, bsums, off, N);
    hipMemcpyAsync(cursor, off, (size_t)N * sizeof(int), hipMemcpyDeviceToDevice, stream);
    fill_kernel<<<edgeGrid, 256, 0, stream>>>(src, dst, cursor, col, E);

    // ---- conv1: xw = features @ W1 ; h1 = csr_agg(xw) ----
    gemm_nn128<<<gemmGrid, 256, 0, stream>>>(features, W1, bufA, N, 0);
    csr_agg<<<aggGrid, 256, 0, stream>>>((const float4*)bufA, off, col, (float4*)bufB, N);

    // ---- conv2: h1w = relu(h1) @ W2 ; h2 = csr_agg(h1w) ----
    gemm_nn128<<<gemmGrid, 256, 0, stream>>>(bufB, W2, bufA, N, 1);
    csr_agg<<<aggGrid, 256, 0, stream>>>((const float4*)bufA, off, col, (float4*)bufB, N);

    // ---- per-graph mean + fc + sigmoid ----
    hipMemsetAsync(pooled, 0, 64 * 128 * sizeof(float), stream);
    pool_kernel<<<(N + POOL_CHUNK - 1) / POOL_CHUNK, 256, 0, stream>>>(
        (const float2*)bufB, gid, pooled, N);
    final_fc<<<1, 1024, 0, stream>>>(pooled, gid, N, W3, out);
}

// Round 4
// 517.426 us; speedup vs baseline: 11.1151x; 1.2652x over previous
//
#include <hip/hip_runtime.h>

#define GEMM_ROWS 32
#define NXCD 8

// C[N,128] = relu_out? relu(A @ W) : (A @ W)
__global__ __launch_bounds__(256) void gemm_nn128(
    const float* __restrict__ A, const float* __restrict__ W,
    float* __restrict__ C, int N, int relu_out)
{
    __shared__ float sW[128 * 128];       // 64 KB
    __shared__ float sA[GEMM_ROWS * 128]; // 16 KB

    const float4* W4 = (const float4*)W;
    float4* sW4 = (float4*)sW;
    #pragma unroll
    for (int i = 0; i < 16; ++i)
        sW4[threadIdx.x + 256 * i] = W4[threadIdx.x + 256 * i];

    int row0 = blockIdx.x * GEMM_ROWS;
    int nrows = N - row0; if (nrows > GEMM_ROWS) nrows = GEMM_ROWS;
    const float4* A4 = (const float4*)(A + (size_t)row0 * 128);
    float4* sA4 = (float4*)sA;
    for (int i = threadIdx.x; i < nrows * 32; i += 256)
        sA4[i] = A4[i];
    __syncthreads();

    int c4 = threadIdx.x & 31;        // output col group: cols 4*c4 .. 4*c4+3
    int r0 = (threadIdx.x >> 5) * 4;  // rows r0 .. r0+3
    float4 acc0 = {0,0,0,0}, acc1 = {0,0,0,0}, acc2 = {0,0,0,0}, acc3 = {0,0,0,0};

    #pragma unroll 8
    for (int k4 = 0; k4 < 32; ++k4) {
        float4 w0 = sW4[(k4*4+0)*32 + c4];
        float4 w1 = sW4[(k4*4+1)*32 + c4];
        float4 w2 = sW4[(k4*4+2)*32 + c4];
        float4 w3 = sW4[(k4*4+3)*32 + c4];
        #define ROW_FMA(acc, i) { \
            float4 a = sA4[(r0+(i))*32 + k4]; \
            acc.x += a.x*w0.x + a.y*w1.x + a.z*w2.x + a.w*w3.x; \
            acc.y += a.x*w0.y + a.y*w1.y + a.z*w2.y + a.w*w3.y; \
            acc.z += a.x*w0.z + a.y*w1.z + a.z*w2.z + a.w*w3.z; \
            acc.w += a.x*w0.w + a.y*w1.w + a.z*w2.w + a.w*w3.w; }
        ROW_FMA(acc0, 0) ROW_FMA(acc1, 1) ROW_FMA(acc2, 2) ROW_FMA(acc3, 3)
        #undef ROW_FMA
    }

    if (relu_out) {
        #define RELU4(a) { a.x=fmaxf(a.x,0.f); a.y=fmaxf(a.y,0.f); a.z=fmaxf(a.z,0.f); a.w=fmaxf(a.w,0.f); }
        RELU4(acc0) RELU4(acc1) RELU4(acc2) RELU4(acc3)
        #undef RELU4
    }

    float4* C4 = (float4*)(C + (size_t)row0 * 128);
    if (r0 + 0 < nrows) C4[(r0+0)*32 + c4] = acc0;
    if (r0 + 1 < nrows) C4[(r0+1)*32 + c4] = acc1;
    if (r0 + 2 < nrows) C4[(r0+2)*32 + c4] = acc2;
    if (r0 + 3 < nrows) C4[(r0+3)*32 + c4] = acc3;
}

// ---------- CSR build (XCD-partitioned by dst range for L2 locality) ----------

__global__ __launch_bounds__(256) void hist_xcd(
    const int* __restrict__ dst, int* __restrict__ deg, int E, int N)
{
    int x  = blockIdx.x & (NXCD - 1);
    int bi = blockIdx.x >> 3;
    int K  = gridDim.x >> 3;
    int chunk = (N + NXCD - 1) / NXCD;
    int lo = x * chunk;
    int hi = lo + chunk; if (hi > N) hi = N;
    for (int e = bi * 256 + threadIdx.x; e < E; e += K * 256) {
        int d = dst[e];
        if (d >= lo && d < hi) atomicAdd(&deg[d], 1);
    }
}

__global__ __launch_bounds__(1024) void scan_partial(
    const int* __restrict__ deg, int* __restrict__ bsums, int N)
{
    __shared__ int sw[16];
    int idx = blockIdx.x * 1024 + threadIdx.x;
    int v = (idx < N) ? deg[idx] : 0;
    #pragma unroll
    for (int o = 32; o; o >>= 1) v += __shfl_down(v, o, 64);
    if ((threadIdx.x & 63) == 0) sw[threadIdx.x >> 6] = v;
    __syncthreads();
    if (threadIdx.x < 16) {
        int x = sw[threadIdx.x];
        #pragma unroll
        for (int o = 8; o; o >>= 1) x += __shfl_down(x, o, 16);
        if (threadIdx.x == 0) bsums[blockIdx.x] = x;
    }
}

__global__ void scan_exclusive_small(int* bsums, int nb)
{
    if (threadIdx.x == 0) {
        int run = 0;
        for (int i = 0; i < nb; ++i) { int t = bsums[i]; bsums[i] = run; run += t; }
    }
}

__global__ __launch_bounds__(1024) void scan_final(
    const int* __restrict__ deg, const int* __restrict__ bsums,
    int* __restrict__ off, int N)
{
    __shared__ int s[1024];
    int t = threadIdx.x;
    int idx = blockIdx.x * 1024 + t;
    int v = (idx < N) ? deg[idx] : 0;
    s[t] = v;
    __syncthreads();
    #pragma unroll
    for (int o = 1; o < 1024; o <<= 1) {
        int x = (t >= o) ? s[t - o] : 0;
        __syncthreads();
        s[t] += x;
        __syncthreads();
    }
    if (idx <= N) off[idx] = s[t] - v + bsums[blockIdx.x];
}

__global__ __launch_bounds__(256) void fill_xcd(
    const int* __restrict__ src, const int* __restrict__ dst,
    int* __restrict__ cursor, int* __restrict__ col, int E, int N)
{
    int x  = blockIdx.x & (NXCD - 1);
    int bi = blockIdx.x >> 3;
    int K  = gridDim.x >> 3;
    int chunk = (N + NXCD - 1) / NXCD;
    int lo = x * chunk;
    int hi = lo + chunk; if (hi > N) hi = N;
    for (int e = bi * 256 + threadIdx.x; e < E; e += K * 256) {
        int d = dst[e];
        if (d >= lo && d < hi) {
            int pos = atomicAdd(&cursor[d], 1);
            col[pos] = src[e];
        }
    }
}

// ---------- CSR aggregation: H[v] = sum_{e: dst=v} X[col[e]] ----------
__global__ __launch_bounds__(256) void csr_agg(
    const float4* __restrict__ X, const int* __restrict__ off,
    const int* __restrict__ col, float4* __restrict__ H, int N)
{
    int v = blockIdx.x * 8 + (threadIdx.x >> 5);
    if (v >= N) return;
    int lane = threadIdx.x & 31;
    int beg = off[v], end = off[v + 1];
    float4 acc = {0.f, 0.f, 0.f, 0.f};
    int i = beg;
    for (; i + 1 < end; i += 2) {
        int s0 = col[i], s1 = col[i + 1];
        float4 x0 = X[(size_t)s0 * 32 + lane];
        float4 x1 = X[(size_t)s1 * 32 + lane];
        acc.x += x0.x + x1.x; acc.y += x0.y + x1.y;
        acc.z += x0.z + x1.z; acc.w += x0.w + x1.w;
    }
    if (i < end) {
        int s0 = col[i];
        float4 x0 = X[(size_t)s0 * 32 + lane];
        acc.x += x0.x; acc.y += x0.y; acc.z += x0.z; acc.w += x0.w;
    }
    H[(size_t)v * 32 + lane] = acc;
}

// ---------- pooling: register accumulate, flush on gid change ----------
#define POOL_CHUNK 128
__global__ __launch_bounds__(256) void pool_kernel(
    const float2* __restrict__ H2, const int* __restrict__ gid,
    float* __restrict__ pooled, int N)
{
    int c = threadIdx.x & 63;       // float2 col: cols 2c, 2c+1
    int stripe = threadIdx.x >> 6;  // 0..3
    int n0 = blockIdx.x * POOL_CHUNK;
    int nend = n0 + POOL_CHUNK; if (nend > N) nend = N;
    float2 acc = {0.f, 0.f};
    int curg = -1;
    for (int n = n0 + stripe; n < nend; n += 4) {
        int g = gid[n];
        float2 v = H2[(size_t)n * 64 + c];
        if (g != curg) {
            if (curg >= 0) {
                unsafeAtomicAdd(&pooled[curg * 128 + 2 * c],     acc.x);
                unsafeAtomicAdd(&pooled[curg * 128 + 2 * c + 1], acc.y);
            }
            curg = g; acc.x = 0.f; acc.y = 0.f;
        }
        acc.x += v.x; acc.y += v.y;
    }
    if (curg >= 0) {
        unsafeAtomicAdd(&pooled[curg * 128 + 2 * c],     acc.x);
        unsafeAtomicAdd(&pooled[curg * 128 + 2 * c + 1], acc.y);
    }
}

// ---------- fused tail: W23 = W2@W3 (LDS); out = sigmoid((pooled/cnt)@W23) ----------
__global__ __launch_bounds__(1024) void final_fused(
    const float* __restrict__ pooled, const int* __restrict__ gid, int N,
    const float* __restrict__ W2, const float* __restrict__ W3,
    float* __restrict__ out)
{
    __shared__ float sW23[128 * 16]; // 8 KB
    __shared__ int lb[65];
    int t = threadIdx.x;
    if (t <= 64) {
        int lo = 0, hi = N;
        while (lo < hi) { int mid = (lo + hi) >> 1; if (gid[mid] < t) lo = mid + 1; else hi = mid; }
        lb[t] = lo;
    }
    for (int idx = t; idx < 2048; idx += 1024) {
        int k = idx >> 4, o = idx & 15;
        float a = 0.f;
        #pragma unroll 16
        for (int j = 0; j < 128; ++j)
            a += W2[k * 128 + j] * W3[j * 16 + o];
        sW23[idx] = a;
    }
    __syncthreads();
    int g = t >> 4, o = t & 15;
    float cnt = fmaxf((float)(lb[g + 1] - lb[g]), 1.0f);
    float acc = 0.f;
    #pragma unroll 16
    for (int k = 0; k < 128; ++k)
        acc += pooled[g * 128 + k] * sW23[k * 16 + o];
    acc /= cnt;
    out[g * 16 + o] = 1.0f / (1.0f + __expf(-acc));
}

extern "C" void kernel_launch(void* const* d_in, const int* in_sizes, int n_in,
                              void* d_out, int out_size, void* d_ws, size_t ws_size,
                              hipStream_t stream)
{
    const float* features = (const float*)d_in[0];
    const float* W1       = (const float*)d_in[1];
    const float* W2       = (const float*)d_in[2];
    const float* W3       = (const float*)d_in[3];
    const int*   src      = (const int*)d_in[4];
    const int*   dst      = (const int*)d_in[5];
    const int*   gid      = (const int*)d_in[6];
    int N = in_sizes[0] / 128;
    int E = in_sizes[4];
    float* out = (float*)d_out;

    size_t bufBytes = (size_t)N * 128 * sizeof(float);
    char* ws = (char*)d_ws;
    size_t p = 0;
    auto alloc = [&](size_t bytes) { void* r = ws + p; p = (p + bytes + 255) & ~(size_t)255; return r; };
    float* bufA   = (float*)alloc(bufBytes);           // t = agg(features); later q = agg(h1)
    float* bufB   = (float*)alloc(bufBytes);           // h1 = relu(t @ W1)
    float* pooled = (float*)alloc(64 * 128 * sizeof(float));
    int*   deg    = (int*)alloc((size_t)N * sizeof(int));
    int*   off    = (int*)alloc((size_t)(N + 1) * sizeof(int));
    int*   cursor = (int*)alloc((size_t)N * sizeof(int));
    int*   col    = (int*)alloc((size_t)E * sizeof(int));
    int*   bsums  = (int*)alloc(256 * sizeof(int));

    int gemmGrid = (N + GEMM_ROWS - 1) / GEMM_ROWS;
    int aggGrid  = (N + 7) / 8;
    int scanGrid = (N + 1024) / 1024; // covers idx == N too
    int xcdGrid  = 1024;              // 128 blocks per XCD slot

    // ---- CSR build (by dst) ----
    hipMemsetAsync(deg, 0, (size_t)N * sizeof(int), stream);
    hist_xcd<<<xcdGrid, 256, 0, stream>>>(dst, deg, E, N);
    scan_partial<<<scanGrid, 1024, 0, stream>>>(deg, bsums, N);
    scan_exclusive_small<<<1, 64, 0, stream>>>(bsums, scanGrid);
    scan_final<<<scanGrid, 1024, 0, stream>>>(deg, bsums, off, N);
    hipMemcpyAsync(cursor, off, (size_t)N * sizeof(int), hipMemcpyDeviceToDevice, stream);
    fill_xcd<<<xcdGrid, 256, 0, stream>>>(src, dst, cursor, col, E, N);

    // ---- t = agg(features) ; h1 = relu(t @ W1) ; q = agg(h1) ----
    csr_agg<<<aggGrid, 256, 0, stream>>>((const float4*)features, off, col, (float4*)bufA, N);
    gemm_nn128<<<gemmGrid, 256, 0, stream>>>(bufA, W1, bufB, N, 1);
    csr_agg<<<aggGrid, 256, 0, stream>>>((const float4*)bufB, off, col, (float4*)bufA, N);

    // ---- per-graph mean, fused (W2@W3) + sigmoid ----
    hipMemsetAsync(pooled, 0, 64 * 128 * sizeof(float), stream);
    pool_kernel<<<(N + POOL_CHUNK - 1) / POOL_CHUNK, 256, 0, stream>>>(
        (const float2*)bufA, gid, pooled, N);
    final_fused<<<1, 1024, 0, stream>>>(pooled, gid, N, W2, W3, out);
}

// Round 5
// 500.157 us; speedup vs baseline: 11.4989x; 1.0345x over previous
//
#include <hip/hip_runtime.h>

#define GEMM_ROWS 32
#define NXCD 8
#define PA_NB 256   // pa_gemm blocks (partial buffers)

__device__ __forceinline__ unsigned int f2bf(float f) {
    unsigned int u = __float_as_uint(f);
    return (u + 0x7fffu + ((u >> 16) & 1u)) >> 16;   // RNE, inputs are normal floats
}

// ---------- features f32 -> bf16 (packed 2/uint) ----------
__global__ __launch_bounds__(256) void fconv(
    const float4* __restrict__ F4, uint4* __restrict__ B4, long long n8)
{
    long long t = (long long)blockIdx.x * 256 + threadIdx.x;
    if (t >= n8) return;
    float4 a = F4[2 * t], b = F4[2 * t + 1];
    uint4 o;
    o.x = f2bf(a.x) | (f2bf(a.y) << 16);
    o.y = f2bf(a.z) | (f2bf(a.w) << 16);
    o.z = f2bf(b.x) | (f2bf(b.y) << 16);
    o.w = f2bf(b.z) | (f2bf(b.w) << 16);
    B4[t] = o;
}

// C[N,128] = relu_out? relu(A @ W) : (A @ W).  In-place (C==A) safe: block
// stages its 32 rows in LDS before any write.
__global__ __launch_bounds__(256) void gemm_nn128(
    const float* __restrict__ A, const float* __restrict__ W,
    float* __restrict__ C, int N, int relu_out)
{
    __shared__ float sW[128 * 128];
    __shared__ float sA[GEMM_ROWS * 128];

    const float4* W4 = (const float4*)W;
    float4* sW4 = (float4*)sW;
    #pragma unroll
    for (int i = 0; i < 16; ++i)
        sW4[threadIdx.x + 256 * i] = W4[threadIdx.x + 256 * i];

    int row0 = blockIdx.x * GEMM_ROWS;
    int nrows = N - row0; if (nrows > GEMM_ROWS) nrows = GEMM_ROWS;
    const float4* A4 = (const float4*)(A + (size_t)row0 * 128);
    float4* sA4 = (float4*)sA;
    for (int i = threadIdx.x; i < nrows * 32; i += 256)
        sA4[i] = A4[i];
    __syncthreads();

    int c4 = threadIdx.x & 31;
    int r0 = (threadIdx.x >> 5) * 4;
    float4 acc0 = {0,0,0,0}, acc1 = {0,0,0,0}, acc2 = {0,0,0,0}, acc3 = {0,0,0,0};

    #pragma unroll 8
    for (int k4 = 0; k4 < 32; ++k4) {
        float4 w0 = sW4[(k4*4+0)*32 + c4];
        float4 w1 = sW4[(k4*4+1)*32 + c4];
        float4 w2 = sW4[(k4*4+2)*32 + c4];
        float4 w3 = sW4[(k4*4+3)*32 + c4];
        #define ROW_FMA(acc, i) { \
            float4 a = sA4[(r0+(i))*32 + k4]; \
            acc.x += a.x*w0.x + a.y*w1.x + a.z*w2.x + a.w*w3.x; \
            acc.y += a.x*w0.y + a.y*w1.y + a.z*w2.y + a.w*w3.y; \
            acc.z += a.x*w0.z + a.y*w1.z + a.z*w2.z + a.w*w3.z; \
            acc.w += a.x*w0.w + a.y*w1.w + a.z*w2.w + a.w*w3.w; }
        ROW_FMA(acc0, 0) ROW_FMA(acc1, 1) ROW_FMA(acc2, 2) ROW_FMA(acc3, 3)
        #undef ROW_FMA
    }

    if (relu_out) {
        #define RELU4(a) { a.x=fmaxf(a.x,0.f); a.y=fmaxf(a.y,0.f); a.z=fmaxf(a.z,0.f); a.w=fmaxf(a.w,0.f); }
        RELU4(acc0) RELU4(acc1) RELU4(acc2) RELU4(acc3)
        #undef RELU4
    }

    float4* C4 = (float4*)(C + (size_t)row0 * 128);
    if (r0 + 0 < nrows) C4[(r0+0)*32 + c4] = acc0;
    if (r0 + 1 < nrows) C4[(r0+1)*32 + c4] = acc1;
    if (r0 + 2 < nrows) C4[(r0+2)*32 + c4] = acc2;
    if (r0 + 3 < nrows) C4[(r0+3)*32 + c4] = acc3;
}

// ---------- CSR build (XCD-partitioned by dst range) ----------

__global__ __launch_bounds__(256) void hist_xcd(
    const int* __restrict__ dst, int* __restrict__ deg, int E, int N)
{
    int x  = blockIdx.x & (NXCD - 1);
    int bi = blockIdx.x >> 3;
    int K  = gridDim.x >> 3;
    int chunk = (N + NXCD - 1) / NXCD;
    int lo = x * chunk;
    int hi = lo + chunk; if (hi > N) hi = N;
    for (int e = bi * 256 + threadIdx.x; e < E; e += K * 256) {
        int d = dst[e];
        if (d >= lo && d < hi) atomicAdd(&deg[d], 1);
    }
}

__global__ __launch_bounds__(1024) void scan_partial(
    const int* __restrict__ deg, int* __restrict__ bsums, int N)
{
    __shared__ int sw[16];
    int idx = blockIdx.x * 1024 + threadIdx.x;
    int v = (idx < N) ? deg[idx] : 0;
    #pragma unroll
    for (int o = 32; o; o >>= 1) v += __shfl_down(v, o, 64);
    if ((threadIdx.x & 63) == 0) sw[threadIdx.x >> 6] = v;
    __syncthreads();
    if (threadIdx.x < 16) {
        int x = sw[threadIdx.x];
        #pragma unroll
        for (int o = 8; o; o >>= 1) x += __shfl_down(x, o, 16);
        if (threadIdx.x == 0) bsums[blockIdx.x] = x;
    }
}

__global__ void scan_exclusive_small(int* bsums, int nb)
{
    if (threadIdx.x == 0) {
        int run = 0;
        for (int i = 0; i < nb; ++i) { int t = bsums[i]; bsums[i] = run; run += t; }
    }
}

__global__ __launch_bounds__(1024) void scan_final(
    const int* __restrict__ deg, const int* __restrict__ bsums,
    int* __restrict__ off, int N)
{
    __shared__ int s[1024];
    int t = threadIdx.x;
    int idx = blockIdx.x * 1024 + t;
    int v = (idx < N) ? deg[idx] : 0;
    s[t] = v;
    __syncthreads();
    #pragma unroll
    for (int o = 1; o < 1024; o <<= 1) {
        int x = (t >= o) ? s[t - o] : 0;
        __syncthreads();
        s[t] += x;
        __syncthreads();
    }
    if (idx <= N) off[idx] = s[t] - v + bsums[blockIdx.x];
}

__global__ __launch_bounds__(256) void fill_xcd(
    const int* __restrict__ src, const int* __restrict__ dst,
    int* __restrict__ cursor, int* __restrict__ col, int E, int N)
{
    int x  = blockIdx.x & (NXCD - 1);
    int bi = blockIdx.x >> 3;
    int K  = gridDim.x >> 3;
    int chunk = (N + NXCD - 1) / NXCD;
    int lo = x * chunk;
    int hi = lo + chunk; if (hi > N) hi = N;
    for (int e = bi * 256 + threadIdx.x; e < E; e += K * 256) {
        int d = dst[e];
        if (d >= lo && d < hi) {
            int pos = atomicAdd(&cursor[d], 1);
            col[pos] = src[e];
        }
    }
}

// ---------- bf16 CSR gather: H[v] = sum_{e: dst=v} X[col[e]] ----------
// 16 lanes/node, each lane owns 8 bf16 cols (one uint4), f32 accumulate.
__global__ __launch_bounds__(256) void csr_agg_bf16(
    const uint4* __restrict__ X, const int* __restrict__ off,
    const int* __restrict__ col, float4* __restrict__ H, int N)
{
    int v = blockIdx.x * 16 + (threadIdx.x >> 4);
    if (v >= N) return;
    int lane = threadIdx.x & 15;
    int beg = off[v], end = off[v + 1];
    float a0=0,a1=0,a2=0,a3=0,a4=0,a5=0,a6=0,a7=0;
    #define ACCUM(u) { \
        a0 += __uint_as_float((u).x << 16); a1 += __uint_as_float((u).x & 0xffff0000u); \
        a2 += __uint_as_float((u).y << 16); a3 += __uint_as_float((u).y & 0xffff0000u); \
        a4 += __uint_as_float((u).z << 16); a5 += __uint_as_float((u).z & 0xffff0000u); \
        a6 += __uint_as_float((u).w << 16); a7 += __uint_as_float((u).w & 0xffff0000u); }
    int i = beg;
    for (; i + 1 < end; i += 2) {
        uint4 x0 = X[(size_t)col[i] * 16 + lane];
        uint4 x1 = X[(size_t)col[i + 1] * 16 + lane];
        ACCUM(x0) ACCUM(x1)
    }
    if (i < end) {
        uint4 x0 = X[(size_t)col[i] * 16 + lane];
        ACCUM(x0)
    }
    #undef ACCUM
    H[(size_t)v * 32 + lane * 2 + 0] = make_float4(a0, a1, a2, a3);
    H[(size_t)v * 32 + lane * 2 + 1] = make_float4(a4, a5, a6, a7);
}

// ---------- PA build: PA32[v][g>>2] byte (g&3) += 1 for each edge v->g ----------
__global__ __launch_bounds__(256) void edge_pa(
    const int* __restrict__ src, const int* __restrict__ dst,
    const int* __restrict__ gid, unsigned int* __restrict__ PA32, int E, int N)
{
    int x  = blockIdx.x & (NXCD - 1);
    int bi = blockIdx.x >> 3;
    int K  = gridDim.x >> 3;
    int chunk = (N + NXCD - 1) / NXCD;
    int lo = x * chunk;
    int hi = lo + chunk; if (hi > N) hi = N;
    for (int e = bi * 256 + threadIdx.x; e < E; e += K * 256) {
        int s = src[e];
        if (s >= lo && s < hi) {
            int g = gid[dst[e]];
            atomicAdd(&PA32[(size_t)s * 16 + (g >> 2)], 1u << ((g & 3) * 8));
        }
    }
}

// ---------- pa_gemm: partial[b][g][c] = sum_{v in block} count(v,g) * Y[v][c] ----------
// thread: word j = t&15 (4 packed g = 4j..4j+3), col group dgrp = t>>4 (8 cols).
__global__ __launch_bounds__(256) void pa_gemm(
    const float4* __restrict__ Y4, const unsigned int* __restrict__ PA32,
    float4* __restrict__ partial, int N)
{
    __shared__ float4 sY4[8 * 32];       // 8 nodes x 128 f32
    __shared__ unsigned int sPA[8 * 16]; // 8 nodes x 16 words

    int b = blockIdx.x;
    int chunk = (N + PA_NB - 1) / PA_NB;
    int v0 = b * chunk;
    int v1 = v0 + chunk; if (v1 > N) v1 = N;

    int t = threadIdx.x;
    int j = t & 15, dgrp = t >> 4;
    float4 acc[4][2];
    #pragma unroll
    for (int i = 0; i < 4; ++i) { acc[i][0] = make_float4(0,0,0,0); acc[i][1] = make_float4(0,0,0,0); }

    for (int vc = v0; vc < v1; vc += 8) {
        int row = t >> 5;
        int vr = vc + row;
        sY4[t] = (vr < v1) ? Y4[(size_t)vr * 32 + (t & 31)] : make_float4(0,0,0,0);
        if (t < 128) {
            int vp = vc + (t >> 4);
            sPA[t] = (vp < v1) ? PA32[(size_t)vp * 16 + (t & 15)] : 0u;
        }
        __syncthreads();
        #pragma unroll
        for (int vv = 0; vv < 8; ++vv) {
            unsigned int pw = sPA[vv * 16 + j];
            float4 y0 = sY4[vv * 32 + dgrp * 2 + 0];
            float4 y1 = sY4[vv * 32 + dgrp * 2 + 1];
            #pragma unroll
            for (int i = 0; i < 4; ++i) {
                float w = (float)((pw >> (i * 8)) & 0xffu);
                acc[i][0].x += w * y0.x; acc[i][0].y += w * y0.y;
                acc[i][0].z += w * y0.z; acc[i][0].w += w * y0.w;
                acc[i][1].x += w * y1.x; acc[i][1].y += w * y1.y;
                acc[i][1].z += w * y1.z; acc[i][1].w += w * y1.w;
            }
        }
        __syncthreads();
    }

    // partial layout: [b][64][128] f32 = [b][2048] float4
    #pragma unroll
    for (int i = 0; i < 4; ++i) {
        int g = j * 4 + i;
        partial[(size_t)b * 2048 + g * 32 + dgrp * 2 + 0] = acc[i][0];
        partial[(size_t)b * 2048 + g * 32 + dgrp * 2 + 1] = acc[i][1];
    }
}

__global__ __launch_bounds__(256) void reduce_partial(
    const float* __restrict__ partial, float* __restrict__ pooled)
{
    int o = blockIdx.x * 256 + threadIdx.x; // 0..8191
    float s = 0.f;
    #pragma unroll 4
    for (int b = 0; b < PA_NB; ++b)
        s += partial[(size_t)b * 8192 + o];
    pooled[o] = s;
}

// ---------- fused tail: W23 = W2@W3 (LDS); out = sigmoid((pooled/cnt)@W23) ----------
__global__ __launch_bounds__(1024) void final_fused(
    const float* __restrict__ pooled, const int* __restrict__ gid, int N,
    const float* __restrict__ W2, const float* __restrict__ W3,
    float* __restrict__ out)
{
    __shared__ float sW23[128 * 16];
    __shared__ int lb[65];
    int t = threadIdx.x;
    if (t <= 64) {
        int lo = 0, hi = N;
        while (lo < hi) { int mid = (lo + hi) >> 1; if (gid[mid] < t) lo = mid + 1; else hi = mid; }
        lb[t] = lo;
    }
    for (int idx = t; idx < 2048; idx += 1024) {
        int k = idx >> 4, o = idx & 15;
        float a = 0.f;
        #pragma unroll 16
        for (int j = 0; j < 128; ++j)
            a += W2[k * 128 + j] * W3[j * 16 + o];
        sW23[idx] = a;
    }
    __syncthreads();
    int g = t >> 4, o = t & 15;
    float cnt = fmaxf((float)(lb[g + 1] - lb[g]), 1.0f);
    float acc = 0.f;
    #pragma unroll 16
    for (int k = 0; k < 128; ++k)
        acc += pooled[g * 128 + k] * sW23[k * 16 + o];
    acc /= cnt;
    out[g * 16 + o] = 1.0f / (1.0f + __expf(-acc));
}

extern "C" void kernel_launch(void* const* d_in, const int* in_sizes, int n_in,
                              void* d_out, int out_size, void* d_ws, size_t ws_size,
                              hipStream_t stream)
{
    const float* features = (const float*)d_in[0];
    const float* W1       = (const float*)d_in[1];
    const float* W2       = (const float*)d_in[2];
    const float* W3       = (const float*)d_in[3];
    const int*   src      = (const int*)d_in[4];
    const int*   dst      = (const int*)d_in[5];
    const int*   gid      = (const int*)d_in[6];
    int N = in_sizes[0] / 128;
    int E = in_sizes[4];
    float* out = (float*)d_out;

    size_t bufBytes = (size_t)N * 128 * sizeof(float);
    char* ws = (char*)d_ws;
    size_t p = 0;
    auto alloc = [&](size_t bytes) { void* r = ws + p; p = (p + bytes + 255) & ~(size_t)255; return r; };
    float* bufA    = (float*)alloc(bufBytes);                       // t, then Y (in-place gemm)
    unsigned int* fbf = (unsigned int*)alloc(bufBytes / 2);         // features bf16
    unsigned int* PA32 = (unsigned int*)alloc((size_t)N * 16 * 4);  // packed counts
    float* partial = (float*)alloc((size_t)PA_NB * 8192 * 4);       // pa_gemm partials (8 MB)
    float* pooled  = (float*)alloc(64 * 128 * sizeof(float));
    int*   deg     = (int*)alloc((size_t)N * sizeof(int));
    int*   off     = (int*)alloc((size_t)(N + 1) * sizeof(int));
    int*   cursor  = (int*)alloc((size_t)N * sizeof(int));
    int*   col     = (int*)alloc((size_t)E * sizeof(int));
    int*   bsums   = (int*)alloc(256 * sizeof(int));

    int gemmGrid = (N + GEMM_ROWS - 1) / GEMM_ROWS;
    int aggGrid  = (N + 15) / 16;
    int scanGrid = (N + 1024) / 1024;
    int xcdGrid  = 1024;
    long long n8 = (long long)N * 16; // uint4 count for fconv

    // ---- features -> bf16 ----
    fconv<<<(int)((n8 + 255) / 256), 256, 0, stream>>>((const float4*)features, (uint4*)fbf, n8);

    // ---- CSR build (by dst) ----
    hipMemsetAsync(deg, 0, (size_t)N * sizeof(int), stream);
    hipMemsetAsync(PA32, 0, (size_t)N * 16 * 4, stream);
    hist_xcd<<<xcdGrid, 256, 0, stream>>>(dst, deg, E, N);
    scan_partial<<<scanGrid, 1024, 0, stream>>>(deg, bsums, N);
    scan_exclusive_small<<<1, 64, 0, stream>>>(bsums, scanGrid);
    scan_final<<<scanGrid, 1024, 0, stream>>>(deg, bsums, off, N);
    hipMemcpyAsync(cursor, off, (size_t)N * sizeof(int), hipMemcpyDeviceToDevice, stream);
    fill_xcd<<<xcdGrid, 256, 0, stream>>>(src, dst, cursor, col, E, N);

    // ---- PA counts (pool x adjacency), independent of CSR ----
    edge_pa<<<xcdGrid, 256, 0, stream>>>(src, dst, gid, PA32, E, N);

    // ---- t = agg(features_bf16); Y = relu(t @ W1) in-place ----
    csr_agg_bf16<<<aggGrid, 256, 0, stream>>>((const uint4*)fbf, off, col, (float4*)bufA, N);
    gemm_nn128<<<gemmGrid, 256, 0, stream>>>(bufA, W1, bufA, N, 1);

    // ---- pooled_q = PA^T . Y via partials ----
    pa_gemm<<<PA_NB, 256, 0, stream>>>((const float4*)bufA, PA32, (float4*)partial, N);
    reduce_partial<<<32, 256, 0, stream>>>(partial, pooled);

    // ---- fused (W2@W3) + mean + sigmoid ----
    final_fused<<<1, 1024, 0, stream>>>(pooled, gid, N, W2, W3, out);
}

// Round 6
// 413.493 us; speedup vs baseline: 13.9089x; 1.2096x over previous
//
#include <hip/hip_runtime.h>

#define NXCD 8
#define PA_NB 256   // pa_gemm blocks (partial buffers)

typedef short bf16x8 __attribute__((ext_vector_type(8)));  // 8 bf16 (4 VGPRs)
typedef float f32x4  __attribute__((ext_vector_type(4)));

union U4S8 { uint4 u; bf16x8 s; };

__device__ __forceinline__ unsigned int f2bf(float f) {
    unsigned int u = __float_as_uint(f);
    return (u + 0x7fffu + ((u >> 16) & 1u)) >> 16;   // RNE
}
__device__ __forceinline__ float bflo(unsigned int u) { return __uint_as_float(u << 16); }
__device__ __forceinline__ float bfhi(unsigned int u) { return __uint_as_float(u & 0xffff0000u); }

// ---------- features f32 -> bf16 (packed 2/uint) ----------
__global__ __launch_bounds__(256) void fconv(
    const float4* __restrict__ F4, uint4* __restrict__ B4, long long n8)
{
    long long t = (long long)blockIdx.x * 256 + threadIdx.x;
    if (t >= n8) return;
    float4 a = F4[2 * t], b = F4[2 * t + 1];
    uint4 o;
    o.x = f2bf(a.x) | (f2bf(a.y) << 16);
    o.y = f2bf(a.z) | (f2bf(a.w) << 16);
    o.z = f2bf(b.x) | (f2bf(b.y) << 16);
    o.w = f2bf(b.z) | (f2bf(b.w) << 16);
    B4[t] = o;
}

// ---------- CSR build (XCD-partitioned by dst range) ----------

__global__ __launch_bounds__(256) void hist_xcd(
    const int* __restrict__ dst, int* __restrict__ deg, int E, int N)
{
    int x  = blockIdx.x & (NXCD - 1);
    int bi = blockIdx.x >> 3;
    int K  = gridDim.x >> 3;
    int chunk = (N + NXCD - 1) / NXCD;
    int lo = x * chunk;
    int hi = lo + chunk; if (hi > N) hi = N;
    for (int e = bi * 256 + threadIdx.x; e < E; e += K * 256) {
        int d = dst[e];
        if (d >= lo && d < hi) atomicAdd(&deg[d], 1);
    }
}

__global__ __launch_bounds__(1024) void scan_partial(
    const int* __restrict__ deg, int* __restrict__ bsums, int N)
{
    __shared__ int sw[16];
    int idx = blockIdx.x * 1024 + threadIdx.x;
    int v = (idx < N) ? deg[idx] : 0;
    #pragma unroll
    for (int o = 32; o; o >>= 1) v += __shfl_down(v, o, 64);
    if ((threadIdx.x & 63) == 0) sw[threadIdx.x >> 6] = v;
    __syncthreads();
    if (threadIdx.x < 16) {
        int x = sw[threadIdx.x];
        #pragma unroll
        for (int o = 8; o; o >>= 1) x += __shfl_down(x, o, 16);
        if (threadIdx.x == 0) bsums[blockIdx.x] = x;
    }
}

__global__ void scan_exclusive_small(int* bsums, int nb)
{
    if (threadIdx.x == 0) {
        int run = 0;
        for (int i = 0; i < nb; ++i) { int t = bsums[i]; bsums[i] = run; run += t; }
    }
}

__global__ __launch_bounds__(1024) void scan_final(
    const int* __restrict__ deg, const int* __restrict__ bsums,
    int* __restrict__ off, int N)
{
    __shared__ int s[1024];
    int t = threadIdx.x;
    int idx = blockIdx.x * 1024 + t;
    int v = (idx < N) ? deg[idx] : 0;
    s[t] = v;
    __syncthreads();
    #pragma unroll
    for (int o = 1; o < 1024; o <<= 1) {
        int x = (t >= o) ? s[t - o] : 0;
        __syncthreads();
        s[t] += x;
        __syncthreads();
    }
    if (idx <= N) off[idx] = s[t] - v + bsums[blockIdx.x];
}

__global__ __launch_bounds__(256) void fill_xcd(
    const int* __restrict__ src, const int* __restrict__ dst,
    int* __restrict__ cursor, int* __restrict__ col, int E, int N)
{
    int x  = blockIdx.x & (NXCD - 1);
    int bi = blockIdx.x >> 3;
    int K  = gridDim.x >> 3;
    int chunk = (N + NXCD - 1) / NXCD;
    int lo = x * chunk;
    int hi = lo + chunk; if (hi > N) hi = N;
    for (int e = bi * 256 + threadIdx.x; e < E; e += K * 256) {
        int d = dst[e];
        if (d >= lo && d < hi) {
            int pos = atomicAdd(&cursor[d], 1);
            col[pos] = src[e];
        }
    }
}

// ---------- bf16 CSR gather: t[v] = sum_{e: dst=v} X[col[e]], bf16 out ----------
__global__ __launch_bounds__(256) void csr_agg_bf16(
    const uint4* __restrict__ X, const int* __restrict__ off,
    const int* __restrict__ col, uint4* __restrict__ T, int N)
{
    int v = blockIdx.x * 16 + (threadIdx.x >> 4);
    if (v >= N) return;
    int lane = threadIdx.x & 15;
    int beg = off[v], end = off[v + 1];
    float a0=0,a1=0,a2=0,a3=0,a4=0,a5=0,a6=0,a7=0;
    #define ACCUM(u) { \
        a0 += bflo((u).x); a1 += bfhi((u).x); \
        a2 += bflo((u).y); a3 += bfhi((u).y); \
        a4 += bflo((u).z); a5 += bfhi((u).z); \
        a6 += bflo((u).w); a7 += bfhi((u).w); }
    int i = beg;
    for (; i + 1 < end; i += 2) {
        uint4 x0 = X[(size_t)col[i] * 16 + lane];
        uint4 x1 = X[(size_t)col[i + 1] * 16 + lane];
        ACCUM(x0) ACCUM(x1)
    }
    if (i < end) {
        uint4 x0 = X[(size_t)col[i] * 16 + lane];
        ACCUM(x0)
    }
    #undef ACCUM
    uint4 o;
    o.x = f2bf(a0) | (f2bf(a1) << 16);
    o.y = f2bf(a2) | (f2bf(a3) << 16);
    o.z = f2bf(a4) | (f2bf(a5) << 16);
    o.w = f2bf(a6) | (f2bf(a7) << 16);
    T[(size_t)v * 16 + lane] = o;
}

// ---------- MFMA GEMM: Y = relu(T @ W1), Y in fragment-native bf16 layout ----------
// T: [N][128] bf16 row-major. W1: [128][128] f32 (k-major). Block: 4 waves,
// 64 rows. LDS: W^T bf16 [c][k], XOR-swizzled (byte ^= (c&7)<<4) for
// conflict-free ds_read_b128 (G4). Wave rb: rows rb*16..+15; 8 col-tiles.
// Y layout: uint2 at [(rb*8+ct)*64 + lane]: (rows 4*(l>>4)+{0,1}, {2,3}) packed,
// col = ct*16 + (l&15).
__global__ __launch_bounds__(256) void gemm_mfma(
    const uint4* __restrict__ T, const float* __restrict__ W,
    uint2* __restrict__ Y, int N, int RB)
{
    __shared__ char sWT[32768];
    int t = threadIdx.x;
    {
        int c = t & 127;
        int xo = (c & 7) << 4;
        #pragma unroll
        for (int i = 0; i < 8; ++i) {
            int kc = (t >> 7) + 2 * i;   // 0..15
            int k0 = kc * 8;
            unsigned int h[8];
            #pragma unroll
            for (int j = 0; j < 8; ++j)
                h[j] = f2bf(W[(k0 + j) * 128 + c]);
            uint4 pk;
            pk.x = h[0] | (h[1] << 16);
            pk.y = h[2] | (h[3] << 16);
            pk.z = h[4] | (h[5] << 16);
            pk.w = h[6] | (h[7] << 16);
            *(uint4*)(sWT + c * 256 + ((k0 * 2) ^ xo)) = pk;
        }
    }
    __syncthreads();

    int wid = t >> 6, l = t & 63;
    int rb = blockIdx.x * 4 + wid;
    if (rb >= RB) return;
    int lrow = l & 15, lg = l >> 4;
    int row = rb * 16 + lrow;

    U4S8 cv;
    bf16x8 a[4];
    #pragma unroll
    for (int kk = 0; kk < 4; ++kk) {
        cv.u = (row < N) ? T[(size_t)row * 16 + kk * 4 + lg] : make_uint4(0,0,0,0);
        a[kk] = cv.s;
    }

    f32x4 acc[8];
    #pragma unroll
    for (int ct = 0; ct < 8; ++ct) acc[ct] = (f32x4){0.f,0.f,0.f,0.f};

    #pragma unroll
    for (int ct = 0; ct < 8; ++ct) {
        int c = ct * 16 + lrow;
        const char* base = sWT + c * 256;
        int xo = (c & 7) << 4;
        #pragma unroll
        for (int kk = 0; kk < 4; ++kk) {
            cv.u = *(const uint4*)(base + ((kk * 64 + lg * 16) ^ xo));
            acc[ct] = __builtin_amdgcn_mfma_f32_16x16x32_bf16(a[kk], cv.s, acc[ct], 0, 0, 0);
        }
    }

    #pragma unroll
    for (int ct = 0; ct < 8; ++ct) {
        uint2 o;
        o.x = f2bf(fmaxf(acc[ct][0], 0.f)) | (f2bf(fmaxf(acc[ct][1], 0.f)) << 16);
        o.y = f2bf(fmaxf(acc[ct][2], 0.f)) | (f2bf(fmaxf(acc[ct][3], 0.f)) << 16);
        Y[((size_t)rb * 8 + ct) * 64 + l] = o;
    }
}

// ---------- PA build: PA32[v][g>>2] byte (g&3) += 1 for each edge v->g ----------
__global__ __launch_bounds__(256) void edge_pa(
    const int* __restrict__ src, const int* __restrict__ dst,
    const int* __restrict__ gid, unsigned int* __restrict__ PA32, int E, int N)
{
    int x  = blockIdx.x & (NXCD - 1);
    int bi = blockIdx.x >> 3;
    int K  = gridDim.x >> 3;
    int chunk = (N + NXCD - 1) / NXCD;
    int lo = x * chunk;
    int hi = lo + chunk; if (hi > N) hi = N;
    for (int e = bi * 256 + threadIdx.x; e < E; e += K * 256) {
        int s = src[e];
        if (s >= lo && s < hi) {
            int g = gid[dst[e]];
            atomicAdd(&PA32[(size_t)s * 16 + (g >> 2)], 1u << ((g & 3) * 8));
        }
    }
}

// ---------- pa_gemm: partial[b][g][c] = sum_{v in chunk} count(v,g) * Y[v][c] ----------
// Y is fragment-native bf16 (see gemm_mfma). chunk is a multiple of 16 so each
// 8-node group lives in one row-block (qb in {0,8}).
__global__ __launch_bounds__(256) void pa_gemm(
    const uint2* __restrict__ Ybf, const unsigned int* __restrict__ PA32,
    float4* __restrict__ partial, int N, int chunk)
{
    __shared__ float sY[8 * 128];
    __shared__ unsigned int sPA[8 * 16];

    int b = blockIdx.x;
    int v0 = b * chunk;
    int v1 = v0 + chunk; if (v1 > N) v1 = N;

    int t = threadIdx.x;
    int j = t & 15, dgrp = t >> 4;
    float4 acc[4][2];
    #pragma unroll
    for (int i = 0; i < 4; ++i) { acc[i][0] = make_float4(0,0,0,0); acc[i][1] = make_float4(0,0,0,0); }

    int ctS = t >> 5, lsub = t & 31;        // staging coords
    int vlocS = (lsub >> 4) * 4;
    int cS = ctS * 16 + (lsub & 15);

    for (int vc = v0; vc < v1; vc += 8) {
        {
            int rb = vc >> 4, qb = vc & 15; // qb in {0,8}
            uint2 u = Ybf[((size_t)rb * 8 + ctS) * 64 + (qb >> 2) * 16 + lsub];
            sY[(vlocS + 0) * 128 + cS] = bflo(u.x);
            sY[(vlocS + 1) * 128 + cS] = bfhi(u.x);
            sY[(vlocS + 2) * 128 + cS] = bflo(u.y);
            sY[(vlocS + 3) * 128 + cS] = bfhi(u.y);
        }
        if (t < 128) {
            int vp = vc + (t >> 4);
            sPA[t] = (vp < v1) ? PA32[(size_t)vp * 16 + (t & 15)] : 0u;
        }
        __syncthreads();
        const float4* sY4 = (const float4*)sY;
        #pragma unroll
        for (int vv = 0; vv < 8; ++vv) {
            unsigned int pw = sPA[vv * 16 + j];
            float4 y0 = sY4[vv * 32 + dgrp * 2 + 0];
            float4 y1 = sY4[vv * 32 + dgrp * 2 + 1];
            #pragma unroll
            for (int i = 0; i < 4; ++i) {
                float w = (float)((pw >> (i * 8)) & 0xffu);
                acc[i][0].x += w * y0.x; acc[i][0].y += w * y0.y;
                acc[i][0].z += w * y0.z; acc[i][0].w += w * y0.w;
                acc[i][1].x += w * y1.x; acc[i][1].y += w * y1.y;
                acc[i][1].z += w * y1.z; acc[i][1].w += w * y1.w;
            }
        }
        __syncthreads();
    }

    #pragma unroll
    for (int i = 0; i < 4; ++i) {
        int g = j * 4 + i;
        partial[(size_t)b * 2048 + g * 32 + dgrp * 2 + 0] = acc[i][0];
        partial[(size_t)b * 2048 + g * 32 + dgrp * 2 + 1] = acc[i][1];
    }
}

__global__ __launch_bounds__(256) void reduce_partial(
    const float* __restrict__ partial, float* __restrict__ pooled)
{
    int o = blockIdx.x * 256 + threadIdx.x; // 0..8191
    float s = 0.f;
    #pragma unroll 4
    for (int b = 0; b < PA_NB; ++b)
        s += partial[(size_t)b * 8192 + o];
    pooled[o] = s;
}

// ---------- fused tail: W23 = W2@W3 (LDS); out = sigmoid((pooled/cnt)@W23) ----------
__global__ __launch_bounds__(1024) void final_fused(
    const float* __restrict__ pooled, const int* __restrict__ gid, int N,
    const float* __restrict__ W2, const float* __restrict__ W3,
    float* __restrict__ out)
{
    __shared__ float sW23[128 * 16];
    __shared__ int lb[65];
    int t = threadIdx.x;
    if (t <= 64) {
        int lo = 0, hi = N;
        while (lo < hi) { int mid = (lo + hi) >> 1; if (gid[mid] < t) lo = mid + 1; else hi = mid; }
        lb[t] = lo;
    }
    for (int idx = t; idx < 2048; idx += 1024) {
        int k = idx >> 4, o = idx & 15;
        float a = 0.f;
        #pragma unroll 16
        for (int jj = 0; jj < 128; ++jj)
            a += W2[k * 128 + jj] * W3[jj * 16 + o];
        sW23[idx] = a;
    }
    __syncthreads();
    int g = t >> 4, o = t & 15;
    float cnt = fmaxf((float)(lb[g + 1] - lb[g]), 1.0f);
    float acc = 0.f;
    #pragma unroll 16
    for (int k = 0; k < 128; ++k)
        acc += pooled[g * 128 + k] * sW23[k * 16 + o];
    acc /= cnt;
    out[g * 16 + o] = 1.0f / (1.0f + __expf(-acc));
}

extern "C" void kernel_launch(void* const* d_in, const int* in_sizes, int n_in,
                              void* d_out, int out_size, void* d_ws, size_t ws_size,
                              hipStream_t stream)
{
    const float* features = (const float*)d_in[0];
    const float* W1       = (const float*)d_in[1];
    const float* W2       = (const float*)d_in[2];
    const float* W3       = (const float*)d_in[3];
    const int*   src      = (const int*)d_in[4];
    const int*   dst      = (const int*)d_in[5];
    const int*   gid      = (const int*)d_in[6];
    int N = in_sizes[0] / 128;
    int E = in_sizes[4];
    float* out = (float*)d_out;

    int RB = (N + 15) / 16;

    char* ws = (char*)d_ws;
    size_t p = 0;
    auto alloc = [&](size_t bytes) { void* r = ws + p; p = (p + bytes + 255) & ~(size_t)255; return r; };
    unsigned int* fbf  = (unsigned int*)alloc((size_t)N * 128 * 2);     // features bf16
    unsigned int* tbf  = (unsigned int*)alloc((size_t)N * 128 * 2);     // t bf16
    uint2*        Ybf  = (uint2*)alloc((size_t)RB * 8 * 64 * 8);        // Y bf16 frag-native
    unsigned int* PA32 = (unsigned int*)alloc((size_t)N * 16 * 4);      // packed counts
    float* partial = (float*)alloc((size_t)PA_NB * 8192 * 4);           // 8 MB
    float* pooled  = (float*)alloc(64 * 128 * sizeof(float));
    int*   deg     = (int*)alloc((size_t)N * sizeof(int));
    int*   off     = (int*)alloc((size_t)(N + 1) * sizeof(int));
    int*   cursor  = (int*)alloc((size_t)N * sizeof(int));
    int*   col     = (int*)alloc((size_t)E * sizeof(int));
    int*   bsums   = (int*)alloc(256 * sizeof(int));

    int aggGrid  = (N + 15) / 16;
    int scanGrid = (N + 1024) / 1024;
    int xcdGrid  = 1024;
    int gGrid    = (RB + 3) / 4;
    int paChunk  = (((N + PA_NB - 1) / PA_NB) + 15) & ~15;
    long long n8 = (long long)N * 16;

    // ---- features -> bf16 ----
    fconv<<<(int)((n8 + 255) / 256), 256, 0, stream>>>((const float4*)features, (uint4*)fbf, n8);

    // ---- CSR build (by dst) + PA counts ----
    hipMemsetAsync(deg, 0, (size_t)N * sizeof(int), stream);
    hipMemsetAsync(PA32, 0, (size_t)N * 16 * 4, stream);
    hist_xcd<<<xcdGrid, 256, 0, stream>>>(dst, deg, E, N);
    scan_partial<<<scanGrid, 1024, 0, stream>>>(deg, bsums, N);
    scan_exclusive_small<<<1, 64, 0, stream>>>(bsums, scanGrid);
    scan_final<<<scanGrid, 1024, 0, stream>>>(deg, bsums, off, N);
    hipMemcpyAsync(cursor, off, (size_t)N * sizeof(int), hipMemcpyDeviceToDevice, stream);
    fill_xcd<<<xcdGrid, 256, 0, stream>>>(src, dst, cursor, col, E, N);
    edge_pa<<<xcdGrid, 256, 0, stream>>>(src, dst, gid, PA32, E, N);

    // ---- t = agg(features_bf16) [bf16]; Y = relu(t @ W1) [bf16 frag] ----
    csr_agg_bf16<<<aggGrid, 256, 0, stream>>>((const uint4*)fbf, off, col, (uint4*)tbf, N);
    gemm_mfma<<<gGrid, 256, 0, stream>>>((const uint4*)tbf, W1, Ybf, N, RB);

    // ---- pooled_q = PA^T . Y ----
    pa_gemm<<<PA_NB, 256, 0, stream>>>(Ybf, PA32, (float4*)partial, N, paChunk);
    reduce_partial<<<32, 256, 0, stream>>>(partial, pooled);

    // ---- fused (W2@W3) + mean + sigmoid ----
    final_fused<<<1, 1024, 0, stream>>>(pooled, gid, N, W2, W3, out);
}